// Round 1
// 408.463 us; speedup vs baseline: 1.0659x; 1.0659x over previous
//
#include <hip/hip_runtime.h>
#include <hip/hip_fp16.h>

#define BB 2048
#define NN 1568
#define CD 48
#define TPB 512
#define WSLOTS 98304   // 3 c * 4 i * 16 d * 512 ts uint4 slots (1.5 MB in d_ws)

// ---- scalar-safe half2 pack/unpack
__device__ __forceinline__ unsigned packh2(float a, float b) {
    __half2 h = __floats2half2_rn(a, b);
    unsigned r; __builtin_memcpy(&r, &h, 4); return r;
}
__device__ __forceinline__ float2 uph2(unsigned v) {
    __half2 h; __builtin_memcpy(&h, &v, 4); return __half22float2(h);
}

// =================== K0: W fp32 -> fp16, swizzled ===================
// Wh slot layout: [ (c*4+i)*16 + d ][ ts ]  (uint4 = 8 fp16 = all e of one d),
// covering n = i*512 + ts. Phase-A wave loads are then fully coalesced:
// lane ts reads consecutive uint4. Pad region (n >= NN) zero-filled.
__global__ __launch_bounds__(256)
void wcast(const float* __restrict__ W, uint4* __restrict__ Wh)
{
    const int id = blockIdx.x * 256 + threadIdx.x;   // 0..24575
    const int ts = id & 511;
    const int r  = id >> 9;        // 0..47
    const int dq = r & 3;          // d quad (4 d per thread)
    const int ci = r >> 2;         // c*4+i, 0..11
    const int i  = ci & 3;
    const int c  = ci >> 2;
    const int n  = i * 512 + ts;
    uint4* dst = Wh + (size_t)ci * 8192 + dq * 4 * 512 + ts;
    if (n < NN) {
        const float* src = W + ((size_t)(c * NN + n)) * 128 + dq * 32;
#pragma unroll
        for (int dd = 0; dd < 4; ++dd) {
            const float4 f0 = *(const float4*)(src + dd * 8);
            const float4 f1 = *(const float4*)(src + dd * 8 + 4);
            uint4 q;
            q.x = packh2(f0.x, f0.y); q.y = packh2(f0.z, f0.w);
            q.z = packh2(f1.x, f1.y); q.w = packh2(f1.z, f1.w);
            dst[dd * 512] = q;
        }
    } else {
        const uint4 z = make_uint4(0u, 0u, 0u, 0u);
#pragma unroll
        for (int dd = 0; dd < 4; ++dd) dst[dd * 512] = z;
    }
}

// =================== K1: fully fused capsule routing ===================
// One 512-thread block per batch. u (1568 x 48 fp16) lives entirely in LDS:
// row stride 25 words (100 B) -> odd word stride -> conflict-free b32 access.
// Phase A: stream W fp16 from L2 (XCD-resident, 1.2 MB/block), compute u,
//          store to LDS, accumulate pass-0 sum (softmax(0) = 1/3 exactly).
// Passes 1-2: stream u from LDS only. u never touches HBM.
__global__ __launch_bounds__(TPB, 1)
void fused(const float* __restrict__ x, const uint4* __restrict__ Wh,
           float* __restrict__ out)
{
    __shared__ unsigned ul[NN * 25];     // 156,800 B
    __shared__ float red[8][CD];         //   1,536 B
    __shared__ float vsh[CD];            //     192 B   => 158,528 <= 163,840

    const int t = threadIdx.x;
    const int w = t >> 6;
    const int b = blockIdx.x;
    const float* xb = x + (size_t)b * NN * 8;

    float acc[CD];
#pragma unroll
    for (int j = 0; j < CD; ++j) acc[j] = 0.f;

    // ---------------- phase A ----------------
#pragma unroll 1
    for (int i = 0; i < 4; ++i) {
        const int n = i * 512 + t;
        if (n < NN) {
            const float4 xa = __ldg((const float4*)(xb + n * 8));
            const float4 xc = __ldg((const float4*)(xb + n * 8 + 4));
            const float x0 = xa.x, x1 = xa.y, x2 = xa.z, x3 = xa.w;
            const float x4 = xc.x, x5 = xc.y, x6 = xc.z, x7 = xc.w;
            unsigned* row = ul + n * 25;

            // C3 must be a literal so acc[] indexing stays static (no scratch).
#define DO_C(C3) { \
            const uint4* wp = Wh + (size_t)((C3) * 4 + i) * 8192 + t; \
            uint4 wr[16]; \
            _Pragma("unroll") \
            for (int d = 0; d < 16; ++d) wr[d] = wp[d * 512]; \
            float uv[16]; \
            _Pragma("unroll") \
            for (int d = 0; d < 16; ++d) { \
                const float2 p0 = uph2(wr[d].x); \
                const float2 p1 = uph2(wr[d].y); \
                const float2 p2 = uph2(wr[d].z); \
                const float2 p3 = uph2(wr[d].w); \
                uv[d] = p0.x*x0 + p0.y*x1 + p1.x*x2 + p1.y*x3 \
                      + p2.x*x4 + p2.y*x5 + p3.x*x6 + p3.y*x7; \
                acc[(C3) * 16 + d] += uv[d]; \
            } \
            _Pragma("unroll") \
            for (int k = 0; k < 8; ++k) \
                row[(C3) * 8 + k] = packh2(uv[2*k], uv[2*k+1]); }

            DO_C(0)
            DO_C(1)
            DO_C(2)
#undef DO_C
        }
    }
    __syncthreads();

#define REDUCE_ACC(ARR) { \
    _Pragma("unroll") \
    for (int j = 0; j < CD; ++j) { \
        float v_ = ARR[j]; \
        v_ += __shfl_xor(v_, 1);  v_ += __shfl_xor(v_, 2); \
        v_ += __shfl_xor(v_, 4);  v_ += __shfl_xor(v_, 8); \
        v_ += __shfl_xor(v_, 16); v_ += __shfl_xor(v_, 32); \
        ARR[j] = v_; \
    } \
    if ((t & 63) == 0) { \
        _Pragma("unroll") \
        for (int j = 0; j < CD; ++j) red[w][j] = ARR[j]; \
    } }

    REDUCE_ACC(acc)
    __syncthreads();
    if (t < CD) {
        const float s = (red[0][t] + red[1][t] + red[2][t] + red[3][t]
                       + red[4][t] + red[5][t] + red[6][t] + red[7][t]) * (1.0f / 3.0f);
        float q = s * s;
        q += __shfl_xor(q, 1); q += __shfl_xor(q, 2); q += __shfl_xor(q, 4); q += __shfl_xor(q, 8);
        vsh[t] = s * sqrtf(q) / (1.f + q);       // v1
    }
    __syncthreads();

    // ---------------- passes 1,2 (u from LDS) ----------------
#pragma unroll 1
    for (int pass = 1; pass <= 2; ++pass) {
        float wv[CD];
#pragma unroll
        for (int j = 0; j < CD; ++j) wv[j] = vsh[j];
        float ac2[CD];
#pragma unroll
        for (int j = 0; j < CD; ++j) ac2[j] = 0.f;

#pragma unroll 1
        for (int i = 0; i < 4; ++i) {
            const int n = i * 512 + t;
            if (n < NN) {
                const unsigned* row = ul + n * 25;
                float2 f[24];
#pragma unroll
                for (int j = 0; j < 24; ++j) f[j] = uph2(row[j]);
                float l0 = 0.f, l1 = 0.f, l2 = 0.f;
#pragma unroll
                for (int j = 0; j < 8; ++j) {
                    l0 += wv[2*j]      * f[j].x      + wv[2*j+1]      * f[j].y;
                    l1 += wv[16+2*j]   * f[8+j].x    + wv[16+2*j+1]   * f[8+j].y;
                    l2 += wv[32+2*j]   * f[16+j].x   + wv[32+2*j+1]   * f[16+j].y;
                }
                // |logit| < ~0.2 — no max-shift needed
                const float e0 = __expf(l0), e1 = __expf(l1), e2 = __expf(l2);
                const float inv = 1.f / (e0 + e1 + e2);
                const float c0 = e0 * inv, c1 = e1 * inv, c2 = e2 * inv;
#pragma unroll
                for (int j = 0; j < 8; ++j) {
                    ac2[2*j]      += c0 * f[j].x;      ac2[2*j+1]      += c0 * f[j].y;
                    ac2[16+2*j]   += c1 * f[8+j].x;    ac2[16+2*j+1]   += c1 * f[8+j].y;
                    ac2[32+2*j]   += c2 * f[16+j].x;   ac2[32+2*j+1]   += c2 * f[16+j].y;
                }
            }
        }
        REDUCE_ACC(ac2)
        __syncthreads();
        if (t < CD) {
            const float s = red[0][t] + red[1][t] + red[2][t] + red[3][t]
                          + red[4][t] + red[5][t] + red[6][t] + red[7][t];
            float q = s * s;
            q += __shfl_xor(q, 1); q += __shfl_xor(q, 2); q += __shfl_xor(q, 4); q += __shfl_xor(q, 8);
            const float v = s * sqrtf(q) / (1.f + q);
            if (pass == 1) vsh[t] += v;                       // w2 = v1 + v2
            else           out[(size_t)b * CD + t] = v;       // final
        }
        __syncthreads();
    }
#undef REDUCE_ACC
}

extern "C" void kernel_launch(void* const* d_in, const int* in_sizes, int n_in,
                              void* d_out, int out_size, void* d_ws, size_t ws_size,
                              hipStream_t stream) {
    (void)in_sizes; (void)n_in; (void)out_size;
    const float* x = (const float*)d_in[0];   // (B, N, 8) fp32
    const float* W = (const float*)d_in[1];   // (1, 3, N, 16, 8) fp32
    if (ws_size < (size_t)WSLOTS * 16) return;
    uint4* Wh = (uint4*)d_ws;

    hipLaunchKernelGGL(wcast, dim3(96),   dim3(256), 0, stream, W, Wh);
    hipLaunchKernelGGL(fused, dim3(BB),   dim3(TPB), 0, stream, x, Wh, (float*)d_out);
}